// Round 3
// baseline (119094.153 us; speedup 1.0000x reference)
//
#include <hip/hip_runtime.h>
#include <cstdint>
#include <cstddef>

#define T_ 512
#define B_ 32
#define D_ 1024
#define L_ 4
#define BD_ (B_*D_)
#define LBD_ (L_*BD_)
#define NWG 16
#define TPB 256
#define EPSF 1e-5f

typedef _Float16 f16x8 __attribute__((ext_vector_type(8)));
typedef float f32x4 __attribute__((ext_vector_type(4)));
typedef float f32x2 __attribute__((ext_vector_type(2)));
typedef unsigned long long u64;

// workspace layout (bytes)
#define WS_BAR    0
#define WS_YSTAT  64
#define WS_STATE1 4096
#define WS_WT     (1u<<20)

// LDS layout (bytes)
#define LDS_A     0          // 32 rows x 2048 fused-k fp16, row stride 4096B, XOR-swizzled
#define LDS_DUMP  131072     // 16 tile-slots x 64 lanes x 16B
#define LDS_PART  147456     // 32 x 8 float2
#define LDS_LN    149504     // 32 float2 (mean, rstd)
#define LDS_YS    149760     // 32 float2 (sum, sumsq)
#define LDS_TOTAL 150528

__device__ __forceinline__ unsigned pk2h(float a, float b){
  _Float16 ha = (_Float16)a, hb = (_Float16)b;
  unsigned short ua = __builtin_bit_cast(unsigned short, ha);
  unsigned short ub = __builtin_bit_cast(unsigned short, hb);
  return (unsigned)ua | ((unsigned)ub<<16);
}
__device__ __forceinline__ f16x8 as_h(uint4 u){ return __builtin_bit_cast(f16x8, u); }

// ---- coherent (cross-XCD, L2-bypassing) state accessors: relaxed agent-scope atomics.
// These emit sc-bit loads/stores that read/write the L3 coherence point WITHOUT any
// L2 invalidate/writeback fences, so weights stay hot in each XCD's L2.
__device__ __forceinline__ f32x2 cload2(const float* p){
  u64 v = __hip_atomic_load((u64*)(void*)p, __ATOMIC_RELAXED, __HIP_MEMORY_SCOPE_AGENT);
  return __builtin_bit_cast(f32x2, v);
}
__device__ __forceinline__ float cload1(const float* p){
  unsigned v = __hip_atomic_load((unsigned*)(void*)p, __ATOMIC_RELAXED, __HIP_MEMORY_SCOPE_AGENT);
  return __builtin_bit_cast(float, v);
}
__device__ __forceinline__ void cstore1(float* p, float v){
  __hip_atomic_store((unsigned*)(void*)p, __builtin_bit_cast(unsigned, v),
                     __ATOMIC_RELAXED, __HIP_MEMORY_SCOPE_AGENT);
}

// Fence-free grid barrier: __syncthreads() drains each wave's vmcnt (coherent state
// stores are then visible at L3); counter + spin are relaxed agent atomics (L2-bypassing).
__device__ __forceinline__ void gbar(unsigned* bar){
  asm volatile("s_waitcnt vmcnt(0)" ::: "memory");
  __syncthreads();
  if (threadIdx.x == 0){
    unsigned old = __hip_atomic_fetch_add(bar, 1u, __ATOMIC_RELAXED, __HIP_MEMORY_SCOPE_AGENT);
    unsigned tgt = (old/NWG + 1u) * (unsigned)NWG;
    while (__hip_atomic_load(bar, __ATOMIC_RELAXED, __HIP_MEMORY_SCOPE_AGENT) < tgt){
      __builtin_amdgcn_s_sleep(2);
    }
  }
  __syncthreads();
}

// ---------------- pre-pass: fp32 (D,D) row-major -> fp16 transposed fused layout ----------------
extern "C" __global__ void __launch_bounds__(256,1) crs_prepass(
    const float* __restrict__ Wf, const float* __restrict__ Uf,
    const float* __restrict__ Wc, const float* __restrict__ Uc,
    unsigned short* __restrict__ WT)
{
  int bid = blockIdx.x;              // (((i*4+sel)*32+ct)*16+kt)
  int kt  = bid & 15;
  int ct  = (bid>>4) & 31;
  int sel = (bid>>9) & 3;            // 0=Wf 1=Uf 2=Wc 3=Uc
  int i   = bid >> 11;
  int tid = threadIdx.x;
  int kq  = tid >> 5;                // 0..7
  int cc  = tid & 31;                // 0..31
  const float* sp;
  if      (sel==0) sp = Wf;
  else if (sel==1) sp = Uf;
  else if (sel==2) sp = Wc;
  else             sp = Uc;
  sp += (size_t)i * 1048576;
  int cl = ct*32 + cc;
  int k0 = kt*64 + kq*8;
  float f[8];
  #pragma unroll
  for (int e=0;e<8;++e){ f[e] = sp[(size_t)(k0+e)*1024 + cl]; }
  int cg = ((sel>>1) ? 1024 : 0) + cl;
  int ks = sel & 1;
  size_t idx = ((size_t)(i*2048 + cg)*2 + ks)*1024 + k0;
  uint4 pk;
  pk.x = pk2h(f[0], f[1]);
  pk.y = pk2h(f[2], f[3]);
  pk.z = pk2h(f[4], f[5]);
  pk.w = pk2h(f[6], f[7]);
  *(uint4*)(WT + idx) = pk;
}

// ---------------- main persistent kernel ----------------
extern "C" __global__ void __launch_bounds__(TPB,1) crs_main(
    const float* __restrict__ x,   const float* __restrict__ st0,
    const float* __restrict__ bfv, const float* __restrict__ bcv,
    const float* __restrict__ pg,  const float* __restrict__ pb,
    const float* __restrict__ sg,  const float* __restrict__ sbv,
    float* __restrict__ y, float* __restrict__ ostate, float* __restrict__ state1,
    const unsigned short* __restrict__ WT,
    unsigned* __restrict__ bar, float* __restrict__ ystat)
{
  extern __shared__ char smem[];
  const int tid  = threadIdx.x;
  const int w    = blockIdx.x;       // 0..15, owns ns-cols [w*64, w*64+64)
  const int lane = tid & 63;
  const int v    = tid >> 6;         // wave id
  const int kh   = v & 1;            // 0: hn*W half, 1: s*U half
  const int ch   = v >> 1;           // column-pair group
  const int l15  = lane & 15;
  const int lg   = lane >> 4;        // 0..3
  const int sw   = (l15 & 7) << 4;   // XOR swizzle for A reads
  const int r    = tid >> 3;         // staging row 0..31
  const int seg  = tid & 7;          // staging k-segment
  const int swr  = (r & 7) << 4;     // XOR swizzle for A writes

  // own-column state lives in registers (layer loop is fully unrolled -> static idx)
  f32x4 sreg[L_][2][2];
  #pragma unroll
  for (int i=0;i<L_;++i){
    #pragma unroll
    for (int rt=0;rt<2;++rt){
      #pragma unroll
      for (int cp=0;cp<2;++cp){
        int colb = w*64 + (2*ch+cp)*16 + l15;
        #pragma unroll
        for (int jj=0;jj<4;++jj){
          int b = rt*16 + lg*4 + jj;
          sreg[i][rt][cp][jj] = st0[(size_t)i*BD_ + (size_t)b*D_ + colb];
        }
      }
    }
  }

  #pragma unroll 1
  for (int t=0; t<T_; ++t){
    float* scur = (t & 1) ? state1 : ostate;
    float* snxt = (t & 1) ? ostate : state1;
    #pragma unroll
    for (int i=0; i<L_; ++i){
      // ---- stack-LN output y[t-1]
      if (i==0 && t>0){
        const float* h3 = scur + 3*(size_t)BD_;
        int b = tid>>3, c8 = (tid&7)*8;
        int col = w*64 + c8;
        float s0 = cload1(ystat + 2*b), q0 = cload1(ystat + 2*b + 1);
        float m  = s0*(1.f/1024.f);
        float var = q0*(1.f/1024.f) - m*m;
        float rs = rsqrtf(var + EPSF);
        const float* hp = h3 + (size_t)b*D_ + col;
        const float4* sg4 = (const float4*)(sg + col);
        const float4* sb4 = (const float4*)(sbv + col);
        float4* yp4 = (float4*)(y + (size_t)(t-1)*BD_ + (size_t)b*D_ + col);
        #pragma unroll
        for (int q=0;q<2;++q){
          f32x2 hA = cload2(hp + q*4), hB = cload2(hp + q*4 + 2);
          float4 gg = sg4[q], bb = sb4[q];
          float4 o;
          o.x = (hA.x-m)*rs*gg.x + bb.x;
          o.y = (hA.y-m)*rs*gg.y + bb.y;
          o.z = (hB.x-m)*rs*gg.z + bb.z;
          o.w = (hB.y-m)*rs*gg.w + bb.w;
          yp4[q] = o;
        }
      }

      // ---- A staging: LN(h) into fused-k [0,1024), state into [1024,2048)
      const float* ssrc = scur + (size_t)i*BD_;
      float sum=0.f, sq=0.f;
      const float4* hv = (const float4*)(x + (size_t)t*BD_ + (size_t)r*D_ + seg*128); // i==0 only
      const float* hp  = (i==0) ? nullptr
                                : (snxt + (size_t)(i-1)*BD_ + (size_t)r*D_ + seg*128);
      if (i==0){
        #pragma unroll 8
        for (int q=0;q<32;++q){
          float4 h4 = hv[q];
          sum += h4.x + h4.y + h4.z + h4.w;
          sq  += h4.x*h4.x + h4.y*h4.y + h4.z*h4.z + h4.w*h4.w;
        }
      } else {
        #pragma unroll 8
        for (int e=0;e<64;++e){
          f32x2 v2 = cload2(hp + e*2);
          sum += v2.x + v2.y;
          sq  += v2.x*v2.x + v2.y*v2.y;
        }
      }
      ((float2*)(smem+LDS_PART))[r*8+seg] = make_float2(sum, sq);
      if (tid < 64) ((float*)(smem+LDS_YS))[tid] = 0.f;
      __syncthreads();
      if (tid < 32){
        const float2* pp = (const float2*)(smem+LDS_PART) + tid*8;
        float s1=0.f, q1=0.f;
        #pragma unroll
        for (int e=0;e<8;++e){ s1 += pp[e].x; q1 += pp[e].y; }
        float m = s1*(1.f/1024.f);
        float var = q1*(1.f/1024.f) - m*m;
        ((float2*)(smem+LDS_LN))[tid] = make_float2(m, rsqrtf(var+EPSF));
      }
      __syncthreads();
      {
        float2 mr = ((const float2*)(smem+LDS_LN))[r];
        const float m = mr.x, rs = mr.y;
        const float4* gv = (const float4*)(pg + (size_t)i*D_ + seg*128);
        const float4* bv = (const float4*)(pb + (size_t)i*D_ + seg*128);
        if (i==0){
          #pragma unroll 4
          for (int jj=0;jj<16;++jj){
            float4 h0 = hv[2*jj], h1 = hv[2*jj+1];
            float4 g0 = gv[2*jj], g1 = gv[2*jj+1];
            float4 p0 = bv[2*jj], p1 = bv[2*jj+1];
            uint4 pk;
            pk.x = pk2h((h0.x-m)*rs*g0.x+p0.x, (h0.y-m)*rs*g0.y+p0.y);
            pk.y = pk2h((h0.z-m)*rs*g0.z+p0.z, (h0.w-m)*rs*g0.w+p0.w);
            pk.z = pk2h((h1.x-m)*rs*g1.x+p1.x, (h1.y-m)*rs*g1.y+p1.y);
            pk.w = pk2h((h1.z-m)*rs*g1.z+p1.z, (h1.w-m)*rs*g1.w+p1.w);
            int fkb = seg*256 + jj*16;
            *(uint4*)(smem + LDS_A + (size_t)r*4096 + (fkb ^ swr)) = pk;
          }
        } else {
          #pragma unroll 4
          for (int jj=0;jj<16;++jj){
            f32x2 a0 = cload2(hp + jj*8 + 0);
            f32x2 a1 = cload2(hp + jj*8 + 2);
            f32x2 a2 = cload2(hp + jj*8 + 4);
            f32x2 a3 = cload2(hp + jj*8 + 6);
            float4 g0 = gv[2*jj], g1 = gv[2*jj+1];
            float4 p0 = bv[2*jj], p1 = bv[2*jj+1];
            uint4 pk;
            pk.x = pk2h((a0.x-m)*rs*g0.x+p0.x, (a0.y-m)*rs*g0.y+p0.y);
            pk.y = pk2h((a1.x-m)*rs*g0.z+p0.z, (a1.y-m)*rs*g0.w+p0.w);
            pk.z = pk2h((a2.x-m)*rs*g1.x+p1.x, (a2.y-m)*rs*g1.y+p1.y);
            pk.w = pk2h((a3.x-m)*rs*g1.z+p1.z, (a3.y-m)*rs*g1.w+p1.w);
            int fkb = seg*256 + jj*16;
            *(uint4*)(smem + LDS_A + (size_t)r*4096 + (fkb ^ swr)) = pk;
          }
        }
        const float* sp2 = ssrc + (size_t)r*D_ + seg*128;
        #pragma unroll 4
        for (int jj=0;jj<16;++jj){
          f32x2 s0 = cload2(sp2 + jj*8 + 0);
          f32x2 s1 = cload2(sp2 + jj*8 + 2);
          f32x2 s2 = cload2(sp2 + jj*8 + 4);
          f32x2 s3 = cload2(sp2 + jj*8 + 6);
          uint4 pk;
          pk.x = pk2h(s0.x, s0.y);
          pk.y = pk2h(s1.x, s1.y);
          pk.z = pk2h(s2.x, s2.y);
          pk.w = pk2h(s3.x, s3.y);
          int fkb = 2048 + seg*256 + jj*16;
          *(uint4*)(smem + LDS_A + (size_t)r*4096 + (fkb ^ swr)) = pk;
        }
      }
      __syncthreads();

      // ---- MFMA k-loop (unchanged)
      f32x4 acc[2][4];
      #pragma unroll
      for (int a1=0;a1<2;++a1){
        #pragma unroll
        for (int a2=0;a2<4;++a2){ acc[a1][a2] = (f32x4){0.f,0.f,0.f,0.f}; }
      }
      const unsigned short *pB0, *pB1, *pB2, *pB3;
      {
        size_t base = (size_t)i*2048;
        size_t koff = (size_t)kh*1024 + (size_t)lg*8;
        int c0 =        w*64 + (2*ch+0)*16 + l15;
        int c1 =        w*64 + (2*ch+1)*16 + l15;
        int c2 = 1024 + w*64 + (2*ch+0)*16 + l15;
        int c3 = 1024 + w*64 + (2*ch+1)*16 + l15;
        pB0 = WT + ((base + c0)*2048 + koff);
        pB1 = WT + ((base + c1)*2048 + koff);
        pB2 = WT + ((base + c2)*2048 + koff);
        pB3 = WT + ((base + c3)*2048 + koff);
      }
      const char* A0 = smem + LDS_A + (size_t)l15*4096;
      const char* A1 = smem + LDS_A + (size_t)(16+l15)*4096;
      #pragma unroll 4
      for (int j=0;j<32;++j){
        int fkb = kh*2048 + j*64 + lg*16;
        int fo  = fkb ^ sw;
        f16x8 a0 = as_h(*(const uint4*)(A0 + fo));
        f16x8 a1 = as_h(*(const uint4*)(A1 + fo));
        f16x8 b0 = as_h(*(const uint4*)(pB0 + j*32));
        f16x8 b1 = as_h(*(const uint4*)(pB1 + j*32));
        f16x8 b2 = as_h(*(const uint4*)(pB2 + j*32));
        f16x8 b3 = as_h(*(const uint4*)(pB3 + j*32));
        acc[0][0] = __builtin_amdgcn_mfma_f32_16x16x32_f16(a0, b0, acc[0][0], 0,0,0);
        acc[1][0] = __builtin_amdgcn_mfma_f32_16x16x32_f16(a1, b0, acc[1][0], 0,0,0);
        acc[0][1] = __builtin_amdgcn_mfma_f32_16x16x32_f16(a0, b1, acc[0][1], 0,0,0);
        acc[1][1] = __builtin_amdgcn_mfma_f32_16x16x32_f16(a1, b1, acc[1][1], 0,0,0);
        acc[0][2] = __builtin_amdgcn_mfma_f32_16x16x32_f16(a0, b2, acc[0][2], 0,0,0);
        acc[1][2] = __builtin_amdgcn_mfma_f32_16x16x32_f16(a1, b2, acc[1][2], 0,0,0);
        acc[0][3] = __builtin_amdgcn_mfma_f32_16x16x32_f16(a0, b3, acc[0][3], 0,0,0);
        acc[1][3] = __builtin_amdgcn_mfma_f32_16x16x32_f16(a1, b3, acc[1][3], 0,0,0);
      }
      __syncthreads();
      if (kh==1){
        #pragma unroll
        for (int rt=0;rt<2;++rt){
          #pragma unroll
          for (int tf=0;tf<4;++tf){
            *(f32x4*)(smem + LDS_DUMP + ((((ch*2+rt)*4+tf)*64 + lane)<<4)) = acc[rt][tf];
          }
        }
      }
      __syncthreads();
      if (kh==0){
        #pragma unroll
        for (int rt=0;rt<2;++rt){
          #pragma unroll
          for (int tf=0;tf<4;++tf){
            acc[rt][tf] += *(const f32x4*)(smem + LDS_DUMP + ((((ch*2+rt)*4+tf)*64 + lane)<<4));
          }
        }
        // epilogue: bias + sigmoid/tanh + state EMA (fp32 master state in regs)
        const size_t sbi = (size_t)i*BD_;
        #pragma unroll
        for (int rt=0;rt<2;++rt){
          #pragma unroll
          for (int cp=0;cp<2;++cp){
            f32x4 f4 = acc[rt][cp];
            f32x4 c4 = acc[rt][2+cp];
            int colb = w*64 + (2*ch+cp)*16 + l15;
            float bfs = bfv[(size_t)i*D_ + colb];
            float bcs = bcv[(size_t)i*D_ + colb];
            #pragma unroll
            for (int jj=0;jj<4;++jj){
              int b = rt*16 + lg*4 + jj;
              float preF = f4[jj] + bfs;
              float preC = c4[jj] + bcs;
              preF = fminf(fmaxf(preF, -30.f), 30.f);
              preC = fminf(fmaxf(preC, -30.f), 30.f);
              float fg = 1.f/(1.f + __expf(-preF));
              float e2 = __expf(-2.f*preC);
              float cd = (1.f - e2)/(1.f + e2);
              float sold = sreg[i][rt][cp][jj];
              float ns = fg*sold + (1.f-fg)*cd;
              sreg[i][rt][cp][jj] = ns;
              cstore1(snxt + sbi + (size_t)b*D_ + colb, ns);
              if (i==3){
                atomicAdd(((float*)(smem+LDS_YS)) + 2*b,     ns);
                atomicAdd(((float*)(smem+LDS_YS)) + 2*b + 1, ns*ns);
              }
            }
          }
        }
      }
      __syncthreads();
      if (i==3 && tid<32){
        float* yl = (float*)(smem+LDS_YS);
        atomicAdd(ystat + 2*tid,     yl[2*tid]);
        atomicAdd(ystat + 2*tid + 1, yl[2*tid+1]);
      }
      if (i==1 && w==0 && tid<64) cstore1(ystat + tid, 0.f);
      gbar(bar);
    }
  }

  // ---- final y[511]
  {
    const float* h3 = ostate + 3*(size_t)BD_;
    int b = tid>>3, c8 = (tid&7)*8;
    int col = w*64 + c8;
    float s0 = cload1(ystat + 2*b), q0 = cload1(ystat + 2*b + 1);
    float m  = s0*(1.f/1024.f);
    float var = q0*(1.f/1024.f) - m*m;
    float rs = rsqrtf(var + EPSF);
    const float* hp = h3 + (size_t)b*D_ + col;
    const float4* sg4 = (const float4*)(sg + col);
    const float4* sb4 = (const float4*)(sbv + col);
    float4* yp4 = (float4*)(y + (size_t)511*BD_ + (size_t)b*D_ + col);
    #pragma unroll
    for (int q=0;q<2;++q){
      f32x2 hA = cload2(hp + q*4), hB = cload2(hp + q*4 + 2);
      float4 gg = sg4[q], bb = sb4[q];
      float4 o;
      o.x = (hA.x-m)*rs*gg.x + bb.x;
      o.y = (hA.y-m)*rs*gg.y + bb.y;
      o.z = (hB.x-m)*rs*gg.z + bb.z;
      o.w = (hB.y-m)*rs*gg.w + bb.w;
      yp4[q] = o;
    }
  }
}

extern "C" void kernel_launch(void* const* d_in, const int* in_sizes, int n_in,
                              void* d_out, int out_size, void* d_ws, size_t ws_size,
                              hipStream_t stream){
  (void)in_sizes; (void)n_in; (void)out_size; (void)ws_size;
  const float* x   = (const float*)d_in[0];
  const float* st0 = (const float*)d_in[1];
  const float* Wf  = (const float*)d_in[2];
  const float* Uf  = (const float*)d_in[3];
  const float* bfv = (const float*)d_in[4];
  const float* Wc  = (const float*)d_in[5];
  const float* Uc  = (const float*)d_in[6];
  const float* bcv = (const float*)d_in[7];
  const float* pg  = (const float*)d_in[8];
  const float* pb  = (const float*)d_in[9];
  const float* sg  = (const float*)d_in[10];
  const float* sbv = (const float*)d_in[11];

  float* y      = (float*)d_out;
  float* ostate = y + (size_t)T_*BD_;

  char* ws = (char*)d_ws;
  unsigned* bar        = (unsigned*)(ws + WS_BAR);
  float* ystat         = (float*)(ws + WS_YSTAT);
  float* state1        = (float*)(ws + WS_STATE1);
  unsigned short* WT   = (unsigned short*)(ws + WS_WT);

  hipMemsetAsync(ws, 0, 4096, stream);
  hipMemcpyAsync(ostate, st0, sizeof(float)*(size_t)LBD_, hipMemcpyDeviceToDevice, stream);
  hipLaunchKernelGGL(crs_prepass, dim3(8192), dim3(256), 0, stream, Wf, Uf, Wc, Uc, WT);
  hipFuncSetAttribute((const void*)crs_main, hipFuncAttributeMaxDynamicSharedMemorySize, LDS_TOTAL);
  hipLaunchKernelGGL(crs_main, dim3(NWG), dim3(TPB), LDS_TOTAL, stream,
                     x, st0, bfv, bcv, pg, pb, sg, sbv, y, ostate, state1, WT, bar, ystat);
}

// Round 4
// 12027.853 us; speedup vs baseline: 9.9015x; 9.9015x over previous
//
#include <hip/hip_runtime.h>
#include <cstdint>
#include <cstddef>

#define T_ 512
#define B_ 32
#define D_ 1024
#define L_ 4
#define BD_ (B_*D_)
#define LBD_ (L_*BD_)
#define TPB 256
#define NWG 256
#define EPSF 1e-5f

typedef _Float16 f16x8 __attribute__((ext_vector_type(8)));
typedef float f32x4 __attribute__((ext_vector_type(4)));
typedef unsigned long long u64;

// workspace layout (bytes)
#define WSO_ROOT   0
#define WSO_GRP    64        // 8 group counters, 256B apart
#define WSO_HSTAT  4096      // [3][4][32][2] f32   (producer layer 0..2, ring-4)
#define WSO_YSTAT  7168      // [4][32][2] f32      (ring-4)
#define WSO_XSTAT  8192      // [512][32][2] f32
#define WSO_ST16   139264    // [4][2][32][1024] u16
#define WSO_H16    663552    // [3][2][32][1024] u16
#define WSO_WT     2097152   // fp16 transposed weights, 32 MB

// LDS layout (bytes)
#define LDS_W     0          // 32 cols x 2048 k fp16, col stride 4096, XOR-swizzled
#define LDS_ABUF  131072     // 2 x (32 rows x 128 k fp16 = 8192), XOR-swizzled
#define LDS_DUMP  147456     // 4 tiles x 64 lanes x 16B
#define LDS_EXC   151552     // 2 tiles x 64 lanes x 16B
#define LDS_NS    153600     // 32 x 16 f32
#define LDS_MRS   155648     // 32 float2
#define LDS_GB    155904     // 1024 x (g,b) fp16-pair
#define LDS_BIAS  160000     // 32 f32 (bf | bc)
#define LDS_SGSB  160128     // 32 f32 (sg | sb)
#define LDS_TOTAL 160256

__device__ __forceinline__ unsigned pk2h(float a, float b){
  _Float16 ha=(_Float16)a, hb=(_Float16)b;
  return (unsigned)__builtin_bit_cast(unsigned short,ha) |
         ((unsigned)__builtin_bit_cast(unsigned short,hb)<<16);
}
__device__ __forceinline__ float h2f(unsigned short u){
  return (float)__builtin_bit_cast(_Float16,u);
}
__device__ __forceinline__ f16x8 as_h(uint4 u){ return __builtin_bit_cast(f16x8,u); }
__device__ __forceinline__ u64 cloadu(const unsigned short* p){
  return __hip_atomic_load((const u64*)(const void*)p, __ATOMIC_RELAXED, __HIP_MEMORY_SCOPE_AGENT);
}
__device__ __forceinline__ void cstoreu(unsigned short* p, u64 v){
  __hip_atomic_store((u64*)(void*)p, v, __ATOMIC_RELAXED, __HIP_MEMORY_SCOPE_AGENT);
}
__device__ __forceinline__ float cload1(const float* p){
  unsigned v=__hip_atomic_load((const unsigned*)(const void*)p,__ATOMIC_RELAXED,__HIP_MEMORY_SCOPE_AGENT);
  return __builtin_bit_cast(float,v);
}
__device__ __forceinline__ void cstore1(float* p, float v){
  __hip_atomic_store((unsigned*)(void*)p,__builtin_bit_cast(unsigned,v),__ATOMIC_RELAXED,__HIP_MEMORY_SCOPE_AGENT);
}
__device__ __forceinline__ uint4 packu64(u64 a, u64 b){
  uint4 u; u.x=(unsigned)a; u.y=(unsigned)(a>>32); u.z=(unsigned)b; u.w=(unsigned)(b>>32); return u;
}

// ---------------- pre-pass 1: fp32 (D,D) row-major -> fp16 transposed fused layout ----------------
// WT flat: (i*2048 + c)*2048 + kf ; c<1024 f-gate, c>=1024 cand ; kf<1024 W-half, kf>=1024 U-half
extern "C" __global__ void __launch_bounds__(256,1) crs_prepass(
    const float* __restrict__ Wf, const float* __restrict__ Uf,
    const float* __restrict__ Wc, const float* __restrict__ Uc,
    unsigned short* __restrict__ WT)
{
  int bid = blockIdx.x;              // (((i*4+sel)*32+ct)*16+kt)
  int kt  = bid & 15;
  int ct  = (bid>>4) & 31;
  int sel = (bid>>9) & 3;            // 0=Wf 1=Uf 2=Wc 3=Uc
  int i   = bid >> 11;
  int tid = threadIdx.x;
  int kq  = tid >> 5;
  int cc  = tid & 31;
  const float* sp;
  if      (sel==0) sp = Wf;
  else if (sel==1) sp = Uf;
  else if (sel==2) sp = Wc;
  else             sp = Uc;
  sp += (size_t)i * 1048576;
  int cl = ct*32 + cc;
  int k0 = kt*64 + kq*8;
  float f[8];
  #pragma unroll
  for (int e=0;e<8;++e){ f[e] = sp[(size_t)(k0+e)*1024 + cl]; }
  int cg = ((sel>>1) ? 1024 : 0) + cl;
  int ks = sel & 1;
  size_t idx = ((size_t)(i*2048 + cg)*2 + ks)*1024 + k0;
  uint4 pk;
  pk.x = pk2h(f[0], f[1]);
  pk.y = pk2h(f[2], f[3]);
  pk.z = pk2h(f[4], f[5]);
  pk.w = pk2h(f[6], f[7]);
  *(uint4*)(WT + idx) = pk;
}

// ---------------- pre-pass 2: x row-stats + initial state -> fp16 ----------------
extern "C" __global__ void __launch_bounds__(256,1) crs_prep2(
    const float* __restrict__ x, const float* __restrict__ st0,
    float* __restrict__ xstat, unsigned short* __restrict__ st16)
{
  __shared__ float2 part[256];
  int bid=blockIdx.x, tid=threadIdx.x;
  int rr=tid>>3, ss=tid&7;
  if (bid<T_){
    const float4* p4=(const float4*)(x+(size_t)bid*BD_+rr*1024+ss*128);
    float s1=0.f,s2=0.f;
    #pragma unroll 8
    for (int q=0;q<32;++q){ float4 a=p4[q]; s1+=a.x+a.y+a.z+a.w; s2+=a.x*a.x+a.y*a.y+a.z*a.z+a.w*a.w; }
    part[tid]=make_float2(s1,s2);
    __syncthreads();
    if (tid<32){
      float a1=0.f,a2=0.f;
      #pragma unroll
      for (int e=0;e<8;++e){ float2 pp=part[tid*8+e]; a1+=pp.x; a2+=pp.y; }
      xstat[bid*64+tid*2]=a1; xstat[bid*64+tid*2+1]=a2;
    }
  } else {
    int i2=bid-T_;
    const float4* p4=(const float4*)(st0+(size_t)i2*BD_+rr*1024+ss*128);
    uint4* dst=(uint4*)(st16+((size_t)i2*2)*32768+rr*1024+ss*128);
    #pragma unroll
    for (int q=0;q<16;++q){
      float4 a=p4[2*q], b=p4[2*q+1];
      uint4 pk; pk.x=pk2h(a.x,a.y); pk.y=pk2h(a.z,a.w); pk.z=pk2h(b.x,b.y); pk.w=pk2h(b.z,b.w);
      dst[q]=pk;
    }
  }
}

// ---------------- main persistent kernel: 256 WGs, layer-skewed pipeline ----------------
extern "C" __global__ void __launch_bounds__(TPB,1) crs_main(
    const float* __restrict__ x, const float* __restrict__ st0,
    const float* __restrict__ bfv, const float* __restrict__ bcv,
    const float* __restrict__ pg, const float* __restrict__ pb,
    const float* __restrict__ sg, const float* __restrict__ sbv,
    float* __restrict__ y, float* __restrict__ ostate,
    const unsigned short* __restrict__ WT, char* __restrict__ ws)
{
  extern __shared__ char smem[];
  const int tid=threadIdx.x, w=blockIdx.x;
  const int li=w>>6, wr=w&63;          // layer, rank-in-layer (owns cols wr*16..+16)
  const int lane=tid&63, v=tid>>6;
  const int cgv=v&1, kh=v>>1;          // wave: col-group (fg/cand), k-half
  const int l15=lane&15, lg=lane>>4;
  const int r=tid>>3, sseg=tid&7;      // staging row / segment
  const int swr=(r&7)<<4;

  unsigned* root=(unsigned*)(ws+WSO_ROOT);
  unsigned* grpc=(unsigned*)(ws+WSO_GRP)+(w>>5)*64;
  float* hstat=(float*)(ws+WSO_HSTAT);
  float* ystat=(float*)(ws+WSO_YSTAT);
  float* xstat=(float*)(ws+WSO_XSTAT);
  unsigned short* st16=(unsigned short*)(ws+WSO_ST16);
  unsigned short* h16=(unsigned short*)(ws+WSO_H16);

  // ---- one-time init: weights -> LDS (swizzled), params -> LDS, state -> regs
  {
    int lc=tid>>3;                                  // local col 0..31 (0-15 fg, 16-31 cand)
    int cgl=(lc>>4)*1024 + wr*16 + (lc&15);
    const unsigned short* src=WT + ((size_t)li*2048+cgl)*2048;
    char* dcol = smem + LDS_W + lc*4096;
    int sw2=(lc&7)<<4;
    #pragma unroll
    for (int n=0;n<32;++n){
      int q=sseg+n*8;
      uint4 d=*(const uint4*)(src+q*8);
      *(uint4*)(dcol + ((q*16)^sw2)) = d;
    }
  }
  for (int k=tid;k<1024;k+=TPB)
    ((unsigned*)(smem+LDS_GB))[k]=pk2h(pg[li*1024+k], pb[li*1024+k]);
  if (tid<16) ((float*)(smem+LDS_BIAS))[tid]=bfv[li*1024+wr*16+tid];
  else if (tid<32) ((float*)(smem+LDS_BIAS))[tid]=bcv[li*1024+wr*16+(tid-16)];
  if (li==3){
    if (tid<16) ((float*)(smem+LDS_SGSB))[tid]=sg[wr*16+tid];
    else if (tid<32) ((float*)(smem+LDS_SGSB))[tid]=sbv[wr*16+(tid-16)];
  }
  f32x4 sreg[2]={{0,0,0,0},{0,0,0,0}}, pns[2]={{0,0,0,0},{0,0,0,0}};
  if (v==0){
    #pragma unroll
    for (int rt=0;rt<2;++rt){
      #pragma unroll
      for (int j=0;j<4;++j){
        int row=rt*16+lg*4+j;
        sreg[rt][j]=st0[(size_t)li*BD_+row*1024+wr*16+l15];
      }
    }
  }
  __syncthreads();

  for (int p=0;p<T_+L_-1;++p){
    int t=p-li;
    if (t>=0 && t<T_){
      // ---- wave0 front-matter: y[t-1] write, ring-slot zeroing, LN stats -> LDS
      if (v==0){
        if (li==3 && t>=1){
          float* stY=ystat+((t-1)&3)*64;
          float gv=((float*)(smem+LDS_SGSB))[l15];
          float bv2=((float*)(smem+LDS_SGSB))[16+l15];
          #pragma unroll
          for (int rt=0;rt<2;++rt){
            #pragma unroll
            for (int j=0;j<4;++j){
              int row=rt*16+lg*4+j;
              float s1=cload1(stY+row*2), s2=cload1(stY+row*2+1);
              float m=s1*(1.f/1024.f);
              float rs=rsqrtf(s2*(1.f/1024.f)-m*m+EPSF);
              y[(size_t)(t-1)*BD_+row*1024+wr*16+l15]=(pns[rt][j]-m)*rs*gv+bv2;
            }
          }
        }
        if (wr==0 && t>=2){
          float* zp=(li<3)? (hstat+(li*4+((t-2)&3))*64) : (ystat+((t-2)&3)*64);
          cstore1(zp+tid,0.f);
        }
        if (tid<32){
          float s1,s2;
          if (li==0){ s1=xstat[t*64+tid*2]; s2=xstat[t*64+tid*2+1]; }
          else { const float* hs=hstat+((li-1)*4+(t&3))*64; s1=cload1(hs+tid*2); s2=cload1(hs+tid*2+1); }
          float m=s1*(1.f/1024.f);
          ((float2*)(smem+LDS_MRS))[tid]=make_float2(m, rsqrtf(s2*(1.f/1024.f)-m*m+EPSF));
        }
      }

      const unsigned short* h16b = (li>0)? (h16 + ((size_t)(li-1)*2+(t&1))*32768) : (const unsigned short*)0;
      const unsigned short* st16b = st16 + ((size_t)li*2+(t&1))*32768;
      const uint4* xb = (const uint4*)(x + (size_t)t*BD_ + (size_t)r*1024);

      uint4 pay[2][2][2];

#define DO_LOAD(c) do{ \
        const int d_=(c)&1; \
        if ((c)<8){ \
          if (li==0){ \
            pay[d_][0][0]=xb[(c)*32+sseg*2];     pay[d_][0][1]=xb[(c)*32+sseg*2+1]; \
            pay[d_][1][0]=xb[(c)*32+(sseg+8)*2]; pay[d_][1][1]=xb[(c)*32+(sseg+8)*2+1]; \
          } else { \
            const unsigned short* hp_=h16b + r*1024 + (c)*128; \
            pay[d_][0][0]=packu64(cloadu(hp_+sseg*8),     cloadu(hp_+sseg*8+4)); \
            pay[d_][1][0]=packu64(cloadu(hp_+(sseg+8)*8), cloadu(hp_+(sseg+8)*8+4)); \
          } \
        } else { \
          const unsigned short* sp_=st16b + r*1024 + ((c)-8)*128; \
          pay[d_][0][0]=packu64(cloadu(sp_+sseg*8),     cloadu(sp_+sseg*8+4)); \
          pay[d_][1][0]=packu64(cloadu(sp_+(sseg+8)*8), cloadu(sp_+(sseg+8)*8+4)); \
        } \
      }while(0)

#define DO_WRITE(c) do{ \
        char* dst_=smem+LDS_ABUF+((c)&1)*8192+r*256; \
        _Pragma("unroll") \
        for (int qi=0;qi<2;++qi){ \
          int q_=sseg+qi*8; \
          uint4 out_; \
          if ((c)<8){ \
            float vr_[8]; \
            uint4 pA=pay[(c)&1][qi][0]; \
            if (li==0){ \
              uint4 pB=pay[(c)&1][qi][1]; \
              vr_[0]=__builtin_bit_cast(float,pA.x); vr_[1]=__builtin_bit_cast(float,pA.y); \
              vr_[2]=__builtin_bit_cast(float,pA.z); vr_[3]=__builtin_bit_cast(float,pA.w); \
              vr_[4]=__builtin_bit_cast(float,pB.x); vr_[5]=__builtin_bit_cast(float,pB.y); \
              vr_[6]=__builtin_bit_cast(float,pB.z); vr_[7]=__builtin_bit_cast(float,pB.w); \
            } else { \
              vr_[0]=h2f((unsigned short)(pA.x&0xffff)); vr_[1]=h2f((unsigned short)(pA.x>>16)); \
              vr_[2]=h2f((unsigned short)(pA.y&0xffff)); vr_[3]=h2f((unsigned short)(pA.y>>16)); \
              vr_[4]=h2f((unsigned short)(pA.z&0xffff)); vr_[5]=h2f((unsigned short)(pA.z>>16)); \
              vr_[6]=h2f((unsigned short)(pA.w&0xffff)); vr_[7]=h2f((unsigned short)(pA.w>>16)); \
            } \
            int k_=(c)*128+q_*8; \
            const uint4* gb4=(const uint4*)(smem+LDS_GB); \
            uint4 gA=gb4[k_/4], gB=gb4[k_/4+1]; \
            float f0=(vr_[0]-mloc)*rsloc*h2f((unsigned short)(gA.x&0xffff))+h2f((unsigned short)(gA.x>>16)); \
            float f1=(vr_[1]-mloc)*rsloc*h2f((unsigned short)(gA.y&0xffff))+h2f((unsigned short)(gA.y>>16)); \
            float f2=(vr_[2]-mloc)*rsloc*h2f((unsigned short)(gA.z&0xffff))+h2f((unsigned short)(gA.z>>16)); \
            float f3=(vr_[3]-mloc)*rsloc*h2f((unsigned short)(gA.w&0xffff))+h2f((unsigned short)(gA.w>>16)); \
            float f4=(vr_[4]-mloc)*rsloc*h2f((unsigned short)(gB.x&0xffff))+h2f((unsigned short)(gB.x>>16)); \
            float f5=(vr_[5]-mloc)*rsloc*h2f((unsigned short)(gB.y&0xffff))+h2f((unsigned short)(gB.y>>16)); \
            float f6=(vr_[6]-mloc)*rsloc*h2f((unsigned short)(gB.z&0xffff))+h2f((unsigned short)(gB.z>>16)); \
            float f7=(vr_[7]-mloc)*rsloc*h2f((unsigned short)(gB.w&0xffff))+h2f((unsigned short)(gB.w>>16)); \
            out_.x=pk2h(f0,f1); out_.y=pk2h(f2,f3); out_.z=pk2h(f4,f5); out_.w=pk2h(f6,f7); \
          } else { out_=pay[(c)&1][qi][0]; } \
          *(uint4*)(dst_+((q_*16)^swr))=out_; \
        } \
      }while(0)

#define DO_MFMA(c) do{ \
        const char* AB_=smem+LDS_ABUF+((c)&1)*8192; \
        _Pragma("unroll") \
        for (int ks=0;ks<2;++ks){ \
          int kloc=kh*64+ks*32+lg*8; \
          int ab=(kloc*2)^((l15&7)<<4); \
          f16x8 b_=as_h(*(const uint4*)(WB + ((((c)*128+kloc)*2)^((l15&7)<<4)))); \
          f16x8 a0_=as_h(*(const uint4*)(AB_+l15*256+ab)); \
          f16x8 a1_=as_h(*(const uint4*)(AB_+(16+l15)*256+ab)); \
          acc0=__builtin_amdgcn_mfma_f32_16x16x32_f16(a0_,b_,acc0,0,0,0); \
          acc1=__builtin_amdgcn_mfma_f32_16x16x32_f16(a1_,b_,acc1,0,0,0); \
        } \
      }while(0)

      f32x4 acc0={0,0,0,0}, acc1={0,0,0,0};
      const char* WB=smem+LDS_W+(cgv*16+l15)*4096;
      DO_LOAD(0); DO_LOAD(1);
      __syncthreads();
      float mloc, rsloc;
      { float2 mr=((const float2*)(smem+LDS_MRS))[r]; mloc=mr.x; rsloc=mr.y; }
      #pragma unroll
      for (int c=0;c<16;++c){
        DO_WRITE(c);
        if (c<14) DO_LOAD(c+2);
        __syncthreads();
        DO_MFMA(c);
      }
#undef DO_LOAD
#undef DO_WRITE
#undef DO_MFMA

      // ---- k-half reduce + epilogue
      __syncthreads();
      if (v>=2){
        *(f32x4*)(smem+LDS_DUMP+((cgv*2+0)*64+lane)*16)=acc0;
        *(f32x4*)(smem+LDS_DUMP+((cgv*2+1)*64+lane)*16)=acc1;
      }
      __syncthreads();
      if (v<2){
        acc0+=*(const f32x4*)(smem+LDS_DUMP+((cgv*2+0)*64+lane)*16);
        acc1+=*(const f32x4*)(smem+LDS_DUMP+((cgv*2+1)*64+lane)*16);
      }
      if (v==1){
        *(f32x4*)(smem+LDS_EXC+(0*64+lane)*16)=acc0;
        *(f32x4*)(smem+LDS_EXC+(1*64+lane)*16)=acc1;
      }
      __syncthreads();
      if (v==0){
        float* stadd=(li<3)? (hstat+(li*4+(t&3))*64) : (ystat+((t&3))*64);
        float bfs=((float*)(smem+LDS_BIAS))[l15];
        float bcs=((float*)(smem+LDS_BIAS))[16+l15];
        float* NS=(float*)(smem+LDS_NS);
        #pragma unroll
        for (int rt=0;rt<2;++rt){
          f32x4 fac = rt? acc1: acc0;
          f32x4 cac = *(const f32x4*)(smem+LDS_EXC+(rt*64+lane)*16);
          #pragma unroll
          for (int j=0;j<4;++j){
            int row=rt*16+lg*4+j;
            float preF=fminf(fmaxf(fac[j]+bfs,-30.f),30.f);
            float preC=fminf(fmaxf(cac[j]+bcs,-30.f),30.f);
            float fg=1.f/(1.f+__expf(-preF));
            float e2=__expf(-2.f*preC);
            float cd=(1.f-e2)/(1.f+e2);
            float ns=fg*sreg[rt][j]+(1.f-fg)*cd;
            sreg[rt][j]=ns;
            if (li==3) pns[rt][j]=ns;
            float s1=ns, s2=ns*ns;
            s1+=__shfl_xor(s1,1); s2+=__shfl_xor(s2,1);
            s1+=__shfl_xor(s1,2); s2+=__shfl_xor(s2,2);
            s1+=__shfl_xor(s1,4); s2+=__shfl_xor(s2,4);
            s1+=__shfl_xor(s1,8); s2+=__shfl_xor(s2,8);
            if (l15==0){ atomicAdd(stadd+row*2,s1); atomicAdd(stadd+row*2+1,s2); }
            NS[row*16+l15]=ns;
          }
        }
        asm volatile("s_waitcnt lgkmcnt(0)" ::: "memory");
        __builtin_amdgcn_sched_barrier(0);
        int row2=lane>>1, hf=lane&1;
        float v0=NS[row2*16+hf*8+0], v1=NS[row2*16+hf*8+1];
        float v2=NS[row2*16+hf*8+2], v3=NS[row2*16+hf*8+3];
        float v4=NS[row2*16+hf*8+4], v5=NS[row2*16+hf*8+5];
        float v6=NS[row2*16+hf*8+6], v7=NS[row2*16+hf*8+7];
        unsigned u0=pk2h(v0,v1),u1=pk2h(v2,v3),u2=pk2h(v4,v5),u3=pk2h(v6,v7);
        u64 A=((u64)u1<<32)|u0, Bv=((u64)u3<<32)|u2;
        size_t so=((size_t)li*2+((t+1)&1))*32768 + row2*1024 + wr*16 + hf*8;
        cstoreu(st16+so,A); cstoreu(st16+so+4,Bv);
        if (li<3){
          size_t ho=((size_t)li*2+(t&1))*32768 + row2*1024 + wr*16 + hf*8;
          cstoreu(h16+ho,A); cstoreu(h16+ho+4,Bv);
        }
        if (t==T_-1){
          float* op=ostate+(size_t)li*BD_+row2*1024+wr*16+hf*8;
          op[0]=v0;op[1]=v1;op[2]=v2;op[3]=v3;op[4]=v4;op[5]=v5;op[6]=v6;op[7]=v7;
        }
      }
    }
    // ---- hierarchical fence-free grid barrier
    asm volatile("s_waitcnt vmcnt(0)" ::: "memory");
    __syncthreads();
    if (tid==0){
      unsigned old=__hip_atomic_fetch_add(grpc,1u,__ATOMIC_RELAXED,__HIP_MEMORY_SCOPE_AGENT);
      if (old==(unsigned)(p*32+31))
        __hip_atomic_fetch_add(root,1u,__ATOMIC_RELAXED,__HIP_MEMORY_SCOPE_AGENT);
      unsigned tgt=(unsigned)((p+1)*8);
      while (__hip_atomic_load(root,__ATOMIC_RELAXED,__HIP_MEMORY_SCOPE_AGENT)<tgt)
        __builtin_amdgcn_s_sleep(2);
    }
    __syncthreads();
  }

  // ---- tail: y[511]
  if (li==3 && v==0){
    float* stY=ystat+((T_-1)&3)*64;
    float gv=((float*)(smem+LDS_SGSB))[l15];
    float bv2=((float*)(smem+LDS_SGSB))[16+l15];
    #pragma unroll
    for (int rt=0;rt<2;++rt){
      #pragma unroll
      for (int j=0;j<4;++j){
        int row=rt*16+lg*4+j;
        float s1=cload1(stY+row*2), s2=cload1(stY+row*2+1);
        float m=s1*(1.f/1024.f);
        float rs=rsqrtf(s2*(1.f/1024.f)-m*m+EPSF);
        y[(size_t)(T_-1)*BD_+row*1024+wr*16+l15]=(pns[rt][j]-m)*rs*gv+bv2;
      }
    }
  }
}

extern "C" void kernel_launch(void* const* d_in, const int* in_sizes, int n_in,
                              void* d_out, int out_size, void* d_ws, size_t ws_size,
                              hipStream_t stream){
  (void)in_sizes; (void)n_in; (void)out_size; (void)ws_size;
  const float* x   = (const float*)d_in[0];
  const float* st0 = (const float*)d_in[1];
  const float* Wf  = (const float*)d_in[2];
  const float* Uf  = (const float*)d_in[3];
  const float* bfv = (const float*)d_in[4];
  const float* Wc  = (const float*)d_in[5];
  const float* Uc  = (const float*)d_in[6];
  const float* bcv = (const float*)d_in[7];
  const float* pg  = (const float*)d_in[8];
  const float* pb  = (const float*)d_in[9];
  const float* sg  = (const float*)d_in[10];
  const float* sbv = (const float*)d_in[11];

  float* y      = (float*)d_out;
  float* ostate = y + (size_t)T_*BD_;
  char* ws = (char*)d_ws;

  hipMemsetAsync(ws, 0, 8192, stream);
  hipLaunchKernelGGL(crs_prepass, dim3(8192), dim3(256), 0, stream,
                     Wf, Uf, Wc, Uc, (unsigned short*)(ws+WSO_WT));
  hipLaunchKernelGGL(crs_prep2, dim3(T_+L_), dim3(256), 0, stream,
                     x, st0, (float*)(ws+WSO_XSTAT), (unsigned short*)(ws+WSO_ST16));
  hipFuncSetAttribute((const void*)crs_main, hipFuncAttributeMaxDynamicSharedMemorySize, LDS_TOTAL);
  hipLaunchKernelGGL(crs_main, dim3(NWG), dim3(TPB), LDS_TOTAL, stream,
                     x, st0, bfv, bcv, pg, pb, sg, sbv, y, ostate,
                     (const unsigned short*)(ws+WSO_WT), ws);
}

// Round 6
// 7931.915 us; speedup vs baseline: 15.0146x; 1.5164x over previous
//
#include <hip/hip_runtime.h>
#include <cstdint>
#include <cstddef>

#define T_ 512
#define B_ 32
#define D_ 1024
#define L_ 4
#define BD_ (B_*D_)
#define TPB 256
#define NWG 256
#define EPSF 1e-5f

typedef _Float16 f16x8 __attribute__((ext_vector_type(8)));
typedef float f32x4 __attribute__((ext_vector_type(4)));
typedef float f32x2 __attribute__((ext_vector_type(2)));
typedef unsigned int u32x4 __attribute__((ext_vector_type(4)));
typedef unsigned long long u64;

// workspace layout (bytes)
#define WSO_ROOT   0
#define WSO_GRP    64
#define WSO_HSTAT  4096
#define WSO_YSTAT  7168
#define WSO_XSTAT  8192
#define WSO_ST16   139264
#define WSO_H16    663552
#define WSO_WT     2097152

// LDS layout (bytes)
#define LDS_W     0        // 32 cols x 2048 fused-k fp16, col stride 4096, XOR-swizzled
#define LDS_DUMP  131072   // 16 tiles x 64 lanes x 16B = 16384
#define LDS_GB    147456   // li0: f32 g[1024]|b[1024] (8KB); li>0: u32 gpk[512]|bpk[512] (4KB)
#define LDS_MRS   155648   // 32 float2
#define LDS_NS    155904   // 32 rows x 80B (20 floats, 16B-aligned stride)
#define LDS_BIAS  158464   // 32 f32 (bf|bc)
#define LDS_SGSB  158592   // 32 f32 (sg|sb)
#define LDS_TOTAL 158720
#define NSTR 20

__device__ __forceinline__ unsigned pk2h(float a, float b){
  _Float16 ha=(_Float16)a, hb=(_Float16)b;
  return (unsigned)__builtin_bit_cast(unsigned short,ha) |
         ((unsigned)__builtin_bit_cast(unsigned short,hb)<<16);
}
__device__ __forceinline__ float cload1(const float* p){
  unsigned v=__hip_atomic_load((const unsigned*)(const void*)p,__ATOMIC_RELAXED,__HIP_MEMORY_SCOPE_AGENT);
  return __builtin_bit_cast(float,v);
}
__device__ __forceinline__ void cstore1(float* p, float v){
  __hip_atomic_store((unsigned*)(void*)p,__builtin_bit_cast(unsigned,v),__ATOMIC_RELAXED,__HIP_MEMORY_SCOPE_AGENT);
}
// 16B coherent store as 2 x u64 relaxed agent-scope atomic stores (compiles; proven in r4)
__device__ __forceinline__ void cstore16(unsigned short* p, unsigned w0, unsigned w1, unsigned w2, unsigned w3){
  u64 lo=((u64)w1<<32)|w0, hi=((u64)w3<<32)|w2;
  __hip_atomic_store((u64*)(void*)p,     lo, __ATOMIC_RELAXED, __HIP_MEMORY_SCOPE_AGENT);
  __hip_atomic_store((u64*)(void*)(p+4), hi, __ATOMIC_RELAXED, __HIP_MEMORY_SCOPE_AGENT);
}

#define GLD(d,vo,sb)    asm volatile("global_load_dwordx4 %0, %1, %2"          : "=v"(d) : "v"(vo), "s"(sb) : "memory")
#define GLD_SC(d,vo,sb) asm volatile("global_load_dwordx4 %0, %1, %2 sc0 sc1" : "=v"(d) : "v"(vo), "s"(sb) : "memory")
#define WAITV(N) do{ asm volatile("s_waitcnt vmcnt(" #N ")" ::: "memory"); __builtin_amdgcn_sched_barrier(0); }while(0)
#define BARS do{ asm volatile("s_waitcnt lgkmcnt(0)" ::: "memory"); __builtin_amdgcn_s_barrier(); }while(0)

// per-chunk A loads: chunks 0-7 = h (LN applied at use), 8-15 = state (raw)
#define LOADC(c) do{ const int s_=(c)&3; \
  if (ISX){ \
    if ((c)<8){ \
      GLD(pay[s_][0][0], vxA+(c)*512,    sbH); GLD(pay[s_][0][1], vxA+(c)*512+16, sbH); \
      GLD(pay[s_][1][0], vxB+(c)*512,    sbH); GLD(pay[s_][1][1], vxB+(c)*512+16, sbH); \
    } else { \
      GLD_SC(pay[s_][0][0], voA+((c)-8)*256, sbS); GLD_SC(pay[s_][1][0], voB+((c)-8)*256, sbS); \
    } \
  } else { \
    if ((c)<8){ GLD_SC(pay[s_][0][0], voA+(c)*256, sbH); GLD_SC(pay[s_][1][0], voB+(c)*256, sbH); } \
    else      { GLD_SC(pay[s_][0][0], voA+((c)-8)*256, sbS); GLD_SC(pay[s_][1][0], voB+((c)-8)*256, sbS); } \
  } \
}while(0)

#define PROC(c) do{ const int s_=(c)&3; f16x8 a0,a1; \
    const int kf_=(c)*128+kq; \
    if ((c)<8){ \
      if (ISX){ \
        f32x4 xa0=__builtin_bit_cast(f32x4,pay[s_][0][0]), xa1=__builtin_bit_cast(f32x4,pay[s_][0][1]); \
        f32x4 xb0=__builtin_bit_cast(f32x4,pay[s_][1][0]), xb1=__builtin_bit_cast(f32x4,pay[s_][1][1]); \
        f32x4 g0=*(const f32x4*)(GBg32+kf_), g1=*(const f32x4*)(GBg32+kf_+4); \
        f32x4 q0=*(const f32x4*)(GBg32+1024+kf_), q1=*(const f32x4*)(GBg32+1024+kf_+4); \
        a0[0]=(_Float16)((xa0[0]*rsA+nmA)*g0[0]+q0[0]); a0[1]=(_Float16)((xa0[1]*rsA+nmA)*g0[1]+q0[1]); \
        a0[2]=(_Float16)((xa0[2]*rsA+nmA)*g0[2]+q0[2]); a0[3]=(_Float16)((xa0[3]*rsA+nmA)*g0[3]+q0[3]); \
        a0[4]=(_Float16)((xa1[0]*rsA+nmA)*g1[0]+q1[0]); a0[5]=(_Float16)((xa1[1]*rsA+nmA)*g1[1]+q1[1]); \
        a0[6]=(_Float16)((xa1[2]*rsA+nmA)*g1[2]+q1[2]); a0[7]=(_Float16)((xa1[3]*rsA+nmA)*g1[3]+q1[3]); \
        a1[0]=(_Float16)((xb0[0]*rsB+nmB)*g0[0]+q0[0]); a1[1]=(_Float16)((xb0[1]*rsB+nmB)*g0[1]+q0[1]); \
        a1[2]=(_Float16)((xb0[2]*rsB+nmB)*g0[2]+q0[2]); a1[3]=(_Float16)((xb0[3]*rsB+nmB)*g0[3]+q0[3]); \
        a1[4]=(_Float16)((xb1[0]*rsB+nmB)*g1[0]+q1[0]); a1[5]=(_Float16)((xb1[1]*rsB+nmB)*g1[1]+q1[1]); \
        a1[6]=(_Float16)((xb1[2]*rsB+nmB)*g1[2]+q1[2]); a1[7]=(_Float16)((xb1[3]*rsB+nmB)*g1[3]+q1[3]); \
      } else { \
        f16x8 g8=*(const f16x8*)(GBg16+(kf_>>1)); \
        f16x8 b8=*(const f16x8*)(GBg16+512+(kf_>>1)); \
        a0=__builtin_bit_cast(f16x8,pay[s_][0][0]); a1=__builtin_bit_cast(f16x8,pay[s_][1][0]); \
        a0=a0*rsA8+nmA8; a0=a0*g8+b8; \
        a1=a1*rsB8+nmB8; a1=a1*g8+b8; \
      } \
    } else { \
      a0=__builtin_bit_cast(f16x8,pay[s_][0][0]); a1=__builtin_bit_cast(f16x8,pay[s_][1][0]); \
    } \
    const int kb_=kf_*2; \
    f16x8 bF=*(const f16x8*)(WF + (kb_^swl)); \
    f16x8 bC=*(const f16x8*)(WC + (kb_^swl)); \
    accF0=__builtin_amdgcn_mfma_f32_16x16x32_f16(a0,bF,accF0,0,0,0); \
    accF1=__builtin_amdgcn_mfma_f32_16x16x32_f16(a1,bF,accF1,0,0,0); \
    accC0=__builtin_amdgcn_mfma_f32_16x16x32_f16(a0,bC,accC0,0,0,0); \
    accC1=__builtin_amdgcn_mfma_f32_16x16x32_f16(a1,bC,accC1,0,0,0); \
  }while(0)

#define CH(c,NW) do{ if ((c)<13) LOADC((c)+3); WAITV(NW); PROC(c); }while(0)

template<int ISX>
__device__ __forceinline__ void stage_pre(u32x4 (&pay)[4][2][2],
    u64 sbH, u64 sbS, int voA, int voB, int vxA, int vxB)
{
  LOADC(0); LOADC(1); LOADC(2);
}

template<int ISX>
__device__ __forceinline__ void chunk_run(char* smem, u32x4 (&pay)[4][2][2],
    u64 sbH, u64 sbS, int voA, int voB, int vxA, int vxB,
    int l15, int kq, float2 mrA, float2 mrB,
    f32x4& accF0, f32x4& accF1, f32x4& accC0, f32x4& accC1)
{
  const char* WF = smem + LDS_W + l15*4096;
  const char* WC = smem + LDS_W + (16+l15)*4096;
  const int swl = (l15&7)<<4;
  const float rsA = mrA.y, rsB = mrB.y;
  const float nmA = -mrA.x*rsA, nmB = -mrB.x*rsB;
  const _Float16 hrA=(_Float16)rsA, hmA=(_Float16)nmA, hrB=(_Float16)rsB, hmB=(_Float16)nmB;
  const f16x8 rsA8={hrA,hrA,hrA,hrA,hrA,hrA,hrA,hrA};
  const f16x8 nmA8={hmA,hmA,hmA,hmA,hmA,hmA,hmA,hmA};
  const f16x8 rsB8={hrB,hrB,hrB,hrB,hrB,hrB,hrB,hrB};
  const f16x8 nmB8={hmB,hmB,hmB,hmB,hmB,hmB,hmB,hmB};
  const unsigned* GBg16 = (const unsigned*)(smem+LDS_GB);
  const float* GBg32 = (const float*)(smem+LDS_GB);

  if (ISX){
    CH(0,12);CH(1,12);CH(2,12);CH(3,12);CH(4,12);CH(5,10);CH(6,8);CH(7,6);
    CH(8,6);CH(9,6);CH(10,6);CH(11,6);CH(12,6);CH(13,4);CH(14,2);CH(15,0);
  } else {
    CH(0,6);CH(1,6);CH(2,6);CH(3,6);CH(4,6);CH(5,6);CH(6,6);CH(7,6);
    CH(8,6);CH(9,6);CH(10,6);CH(11,6);CH(12,6);CH(13,4);CH(14,2);CH(15,0);
  }
}

// ---------------- pre-pass 1: fp32 (D,D) row-major -> fp16 transposed fused layout ----------------
extern "C" __global__ void __launch_bounds__(256,1) crs_prepass(
    const float* __restrict__ Wf, const float* __restrict__ Uf,
    const float* __restrict__ Wc, const float* __restrict__ Uc,
    unsigned short* __restrict__ WT)
{
  int bid = blockIdx.x;
  int kt  = bid & 15;
  int ct  = (bid>>4) & 31;
  int sel = (bid>>9) & 3;
  int i   = bid >> 11;
  int tid = threadIdx.x;
  int kq  = tid >> 5;
  int cc  = tid & 31;
  const float* sp;
  if      (sel==0) sp = Wf;
  else if (sel==1) sp = Uf;
  else if (sel==2) sp = Wc;
  else             sp = Uc;
  sp += (size_t)i * 1048576;
  int cl = ct*32 + cc;
  int k0 = kt*64 + kq*8;
  float f[8];
  #pragma unroll
  for (int e=0;e<8;++e){ f[e] = sp[(size_t)(k0+e)*1024 + cl]; }
  int cg = ((sel>>1) ? 1024 : 0) + cl;
  int ks = sel & 1;
  size_t idx = ((size_t)(i*2048 + cg)*2 + ks)*1024 + k0;
  uint4 pk;
  pk.x = pk2h(f[0], f[1]);
  pk.y = pk2h(f[2], f[3]);
  pk.z = pk2h(f[4], f[5]);
  pk.w = pk2h(f[6], f[7]);
  *(uint4*)(WT + idx) = pk;
}

// ---------------- pre-pass 2: x row-stats + initial state -> fp16 ----------------
extern "C" __global__ void __launch_bounds__(256,1) crs_prep2(
    const float* __restrict__ x, const float* __restrict__ st0,
    float* __restrict__ xstat, unsigned short* __restrict__ st16)
{
  __shared__ float2 part[256];
  int bid=blockIdx.x, tid=threadIdx.x;
  int rr=tid>>3, ss=tid&7;
  if (bid<T_){
    const float4* p4=(const float4*)(x+(size_t)bid*BD_+rr*1024+ss*128);
    float s1=0.f,s2=0.f;
    #pragma unroll 8
    for (int q=0;q<32;++q){ float4 a=p4[q]; s1+=a.x+a.y+a.z+a.w; s2+=a.x*a.x+a.y*a.y+a.z*a.z+a.w*a.w; }
    part[tid]=make_float2(s1,s2);
    __syncthreads();
    if (tid<32){
      float a1=0.f,a2=0.f;
      #pragma unroll
      for (int e=0;e<8;++e){ float2 pp=part[tid*8+e]; a1+=pp.x; a2+=pp.y; }
      xstat[bid*64+tid*2]=a1; xstat[bid*64+tid*2+1]=a2;
    }
  } else {
    int i2=bid-T_;
    const float4* p4=(const float4*)(st0+(size_t)i2*BD_+rr*1024+ss*128);
    uint4* dst=(uint4*)(st16+((size_t)i2*2)*32768+rr*1024+ss*128);
    #pragma unroll
    for (int q=0;q<16;++q){
      float4 a=p4[2*q], b=p4[2*q+1];
      uint4 pk; pk.x=pk2h(a.x,a.y); pk.y=pk2h(a.z,a.w); pk.z=pk2h(b.x,b.y); pk.w=pk2h(b.z,b.w);
      dst[q]=pk;
    }
  }
}

// ---------------- main persistent kernel ----------------
extern "C" __global__ void __launch_bounds__(TPB,1) crs_main(
    const float* __restrict__ x, const float* __restrict__ st0,
    const float* __restrict__ bfv, const float* __restrict__ bcv,
    const float* __restrict__ pg, const float* __restrict__ pb,
    const float* __restrict__ sg, const float* __restrict__ sbv,
    float* __restrict__ y, float* __restrict__ ostate,
    const unsigned short* __restrict__ WT, char* __restrict__ ws)
{
  extern __shared__ char smem[];
  const int tid=threadIdx.x, w=blockIdx.x;
  const int li=w>>6, wr=w&63;
  const int lane=tid&63, v=tid>>6;        // v = k-quarter
  const int l15=lane&15, lg=(lane>>4)&3;
  const int kq = v*32 + lg*8;             // fused-k element offset within a 128-chunk
  const int col=lane&15, rp=lane>>4;      // epilogue mapping
  const int r0=v*8+rp, r1=v*8+4+rp;
  const int sseg=tid&7;

  unsigned* root=(unsigned*)(ws+WSO_ROOT);
  unsigned* grpc=(unsigned*)(ws+WSO_GRP)+(w>>5)*64;
  float* hstat=(float*)(ws+WSO_HSTAT);
  float* ystat=(float*)(ws+WSO_YSTAT);
  float* xstat=(float*)(ws+WSO_XSTAT);
  unsigned short* st16=(unsigned short*)(ws+WSO_ST16);
  unsigned short* h16=(unsigned short*)(ws+WSO_H16);
  float* NSf=(float*)(smem+LDS_NS);
  float* BIAS=(float*)(smem+LDS_BIAS);
  float* SGSB=(float*)(smem+LDS_SGSB);

  // ---- one-time init: weights -> LDS (swizzled)
  {
    int lc=tid>>3;
    int cgl=(lc>>4)*1024 + wr*16 + (lc&15);
    const unsigned short* src=WT + ((size_t)li*2048+cgl)*2048;
    char* dcol = smem + LDS_W + lc*4096;
    int sw2=(lc&7)<<4;
    #pragma unroll
    for (int n=0;n<32;++n){
      int q=sseg+n*8;
      uint4 d=*(const uint4*)(src+q*8);
      *(uint4*)(dcol + ((q*16)^sw2)) = d;
    }
  }
  if (li==0){
    float* g32=(float*)(smem+LDS_GB);
    for (int k=tid;k<1024;k+=TPB){ g32[k]=pg[k]; g32[1024+k]=pb[k]; }
  } else {
    unsigned* g16=(unsigned*)(smem+LDS_GB);
    for (int k=tid;k<512;k+=TPB){
      g16[k]    =pk2h(pg[li*1024+2*k], pg[li*1024+2*k+1]);
      g16[512+k]=pk2h(pb[li*1024+2*k], pb[li*1024+2*k+1]);
    }
  }
  if (tid<16) BIAS[tid]=bfv[li*1024+wr*16+tid];
  else if (tid<32) BIAS[tid]=bcv[li*1024+wr*16+(tid-16)];
  if (li==3){
    if (tid<16) SGSB[tid]=sg[wr*16+tid];
    else if (tid<32) SGSB[tid]=sbv[wr*16+(tid-16)];
  }
  f32x2 sreg, pns={0.f,0.f};
  sreg.x = st0[(size_t)li*BD_ + (size_t)r0*D_ + wr*16+col];
  sreg.y = st0[(size_t)li*BD_ + (size_t)r1*D_ + wr*16+col];
  __syncthreads();

  for (int p=0;p<T_+L_-1;++p){
    int t=p-li;
    if (t>=0 && t<T_){
      // ---- front-matter
      if (li==3 && t>=1){
        const float* stY=ystat+((t-1)&3)*64;
        float gv=SGSB[col], bv=SGSB[16+col];
        float s1=cload1(stY+r0*2), s2=cload1(stY+r0*2+1);
        float m0=s1*(1.f/1024.f);
        float rs0=rsqrtf(s2*(1.f/1024.f)-m0*m0+EPSF);
        y[(size_t)(t-1)*BD_+(size_t)r0*D_+wr*16+col]=(pns.x-m0)*rs0*gv+bv;
        float s3=cload1(stY+r1*2), s4=cload1(stY+r1*2+1);
        float m1=s3*(1.f/1024.f);
        float rs1=rsqrtf(s4*(1.f/1024.f)-m1*m1+EPSF);
        y[(size_t)(t-1)*BD_+(size_t)r1*D_+wr*16+col]=(pns.y-m1)*rs1*gv+bv;
      }
      if (v==0){
        if (wr==0 && t>=2){
          float* zp=(li<3)? (hstat+(li*4+((t-2)&3))*64) : (ystat+((t-2)&3)*64);
          cstore1(zp+tid,0.f);
        }
        if (tid<32){
          float s1,s2;
          if (li==0){ s1=xstat[t*64+tid*2]; s2=xstat[t*64+tid*2+1]; }
          else { const float* hs=hstat+((li-1)*4+(t&3))*64; s1=cload1(hs+tid*2); s2=cload1(hs+tid*2+1); }
          float m=s1*(1.f/1024.f);
          ((float2*)(smem+LDS_MRS))[tid]=make_float2(m, rsqrtf(s2*(1.f/1024.f)-m*m+EPSF));
        }
      }
      asm volatile("s_waitcnt vmcnt(0)" ::: "memory");

      const unsigned short* h16b = (li>0)? (h16 + ((size_t)(li-1)*2+(size_t)(t&1))*32768) : (const unsigned short*)0;
      u64 sbH = (li==0)? (u64)(uintptr_t)(x + (size_t)t*BD_) : (u64)(uintptr_t)h16b;
      u64 sbS = (u64)(uintptr_t)(st16 + ((size_t)li*2+(size_t)(t&1))*32768);
      const int voA = l15*2048 + kq*2, voB = voA + 32768;
      const int vxA = l15*4096 + kq*4, vxB = vxA + 65536;
      u32x4 pay[4][2][2];
      if (li==0) stage_pre<1>(pay, sbH, sbS, voA, voB, vxA, vxB);
      else       stage_pre<0>(pay, sbH, sbS, voA, voB, vxA, vxB);
      BARS;
      float2 mrA=((const float2*)(smem+LDS_MRS))[l15];
      float2 mrB=((const float2*)(smem+LDS_MRS))[16+l15];

      f32x4 accF0={0,0,0,0}, accF1={0,0,0,0}, accC0={0,0,0,0}, accC1={0,0,0,0};
      if (li==0) chunk_run<1>(smem, pay, sbH, sbS, voA, voB, vxA, vxB, l15, kq, mrA, mrB, accF0, accF1, accC0, accC1);
      else       chunk_run<0>(smem, pay, sbH, sbS, voA, voB, vxA, vxB, l15, kq, mrA, mrB, accF0, accF1, accC0, accC1);

      *(f32x4*)(smem+LDS_DUMP + (((v*4+0)*64+lane)<<4)) = accF0;
      *(f32x4*)(smem+LDS_DUMP + (((v*4+1)*64+lane)<<4)) = accF1;
      *(f32x4*)(smem+LDS_DUMP + (((v*4+2)*64+lane)<<4)) = accC0;
      *(f32x4*)(smem+LDS_DUMP + (((v*4+3)*64+lane)<<4)) = accC1;
      BARS;

      {
        const int rtl = v>>1;
        const int lg20 = (v&1)*2, lg21 = (v&1)*2+1;
        float fF0=0.f,fF1=0.f,fC0=0.f,fC1=0.f;
        #pragma unroll
        for (int v2=0;v2<4;++v2){
          const char* db = smem+LDS_DUMP + v2*4096;
          fF0 += *(const float*)(db + (((0+rtl)*64 + lg20*16+col)<<4) + rp*4);
          fF1 += *(const float*)(db + (((0+rtl)*64 + lg21*16+col)<<4) + rp*4);
          fC0 += *(const float*)(db + (((2+rtl)*64 + lg20*16+col)<<4) + rp*4);
          fC1 += *(const float*)(db + (((2+rtl)*64 + lg21*16+col)<<4) + rp*4);
        }
        float bfc=BIAS[col], bcc=BIAS[16+col];
        float preF0=fminf(fmaxf(fF0+bfc,-30.f),30.f);
        float preC0=fminf(fmaxf(fC0+bcc,-30.f),30.f);
        float preF1=fminf(fmaxf(fF1+bfc,-30.f),30.f);
        float preC1=fminf(fmaxf(fC1+bcc,-30.f),30.f);
        float fg0=1.f/(1.f+__expf(-preF0)), e0=__expf(-2.f*preC0);
        float cd0=(1.f-e0)/(1.f+e0);
        float fg1=1.f/(1.f+__expf(-preF1)), e1=__expf(-2.f*preC1);
        float cd1=(1.f-e1)/(1.f+e1);
        float ns0=fg0*sreg.x+(1.f-fg0)*cd0;
        float ns1=fg1*sreg.y+(1.f-fg1)*cd1;
        sreg.x=ns0; sreg.y=ns1;
        if (li==3){ pns.x=ns0; pns.y=ns1; }
        float a1=ns0, a2=ns0*ns0, a3=ns1, a4=ns1*ns1;
        #pragma unroll
        for (int m=1;m<16;m<<=1){
          a1+=__shfl_xor(a1,m); a2+=__shfl_xor(a2,m);
          a3+=__shfl_xor(a3,m); a4+=__shfl_xor(a4,m);
        }
        float* stadd=(li<3)? (hstat+(li*4+(t&3))*64) : (ystat+(t&3)*64);
        if (col==0){
          atomicAdd(stadd+r0*2,   a1); atomicAdd(stadd+r0*2+1, a2);
          atomicAdd(stadd+r1*2,   a3); atomicAdd(stadd+r1*2+1, a4);
        }
        NSf[r0*NSTR+col]=ns0;
        NSf[r1*NSTR+col]=ns1;
      }
      BARS;

      if (lane<16){
        int row = v*8 + (lane>>1), hf = lane&1;
        const float* nr = NSf + row*NSTR + hf*8;
        f32x4 q0 = *(const f32x4*)nr, q1 = *(const f32x4*)(nr+4);
        unsigned w0=pk2h(q0[0],q0[1]), w1=pk2h(q0[2],q0[3]);
        unsigned w2=pk2h(q1[0],q1[1]), w3=pk2h(q1[2],q1[3]);
        unsigned short* sd = st16 + ((size_t)li*2+(size_t)((t+1)&1))*32768 + row*1024 + wr*16 + hf*8;
        cstore16(sd, w0, w1, w2, w3);
        if (li<3){
          unsigned short* hd = h16 + ((size_t)li*2+(size_t)(t&1))*32768 + row*1024 + wr*16 + hf*8;
          cstore16(hd, w0, w1, w2, w3);
        }
        if (t==T_-1){
          float* op = ostate + (size_t)li*BD_ + (size_t)row*D_ + wr*16 + hf*8;
          *(f32x4*)op = q0; *(f32x4*)(op+4) = q1;
        }
      }
    }
    asm volatile("s_waitcnt vmcnt(0)" ::: "memory");
    __syncthreads();
    if (tid==0){
      unsigned old=__hip_atomic_fetch_add(grpc,1u,__ATOMIC_RELAXED,__HIP_MEMORY_SCOPE_AGENT);
      if (old==(unsigned)(p*32+31))
        __hip_atomic_fetch_add(root,1u,__ATOMIC_RELAXED,__HIP_MEMORY_SCOPE_AGENT);
      unsigned tgt=(unsigned)((p+1)*8);
      while (__hip_atomic_load(root,__ATOMIC_RELAXED,__HIP_MEMORY_SCOPE_AGENT)<tgt)
        __builtin_amdgcn_s_sleep(2);
    }
    __syncthreads();
  }

  if (li==3){
    const float* stY=ystat+((T_-1)&3)*64;
    float gv=SGSB[col], bv=SGSB[16+col];
    float s1=cload1(stY+r0*2), s2=cload1(stY+r0*2+1);
    float m0=s1*(1.f/1024.f);
    float rs0=rsqrtf(s2*(1.f/1024.f)-m0*m0+EPSF);
    y[(size_t)(T_-1)*BD_+(size_t)r0*D_+wr*16+col]=(pns.x-m0)*rs0*gv+bv;
    float s3=cload1(stY+r1*2), s4=cload1(stY+r1*2+1);
    float m1=s3*(1.f/1024.f);
    float rs1=rsqrtf(s4*(1.f/1024.f)-m1*m1+EPSF);
    y[(size_t)(T_-1)*BD_+(size_t)r1*D_+wr*16+col]=(pns.y-m1)*rs1*gv+bv;
  }
}

extern "C" void kernel_launch(void* const* d_in, const int* in_sizes, int n_in,
                              void* d_out, int out_size, void* d_ws, size_t ws_size,
                              hipStream_t stream){
  (void)in_sizes; (void)n_in; (void)out_size; (void)ws_size;
  const float* x   = (const float*)d_in[0];
  const float* st0 = (const float*)d_in[1];
  const float* Wf  = (const float*)d_in[2];
  const float* Uf  = (const float*)d_in[3];
  const float* bfv = (const float*)d_in[4];
  const float* Wc  = (const float*)d_in[5];
  const float* Uc  = (const float*)d_in[6];
  const float* bcv = (const float*)d_in[7];
  const float* pg  = (const float*)d_in[8];
  const float* pb  = (const float*)d_in[9];
  const float* sg  = (const float*)d_in[10];
  const float* sbv = (const float*)d_in[11];

  float* y      = (float*)d_out;
  float* ostate = y + (size_t)T_*BD_;
  char* ws = (char*)d_ws;

  (void)hipMemsetAsync(ws, 0, 8192, stream);
  hipLaunchKernelGGL(crs_prepass, dim3(8192), dim3(256), 0, stream,
                     Wf, Uf, Wc, Uc, (unsigned short*)(ws+WSO_WT));
  hipLaunchKernelGGL(crs_prep2, dim3(T_+L_), dim3(256), 0, stream,
                     x, st0, (float*)(ws+WSO_XSTAT), (unsigned short*)(ws+WSO_ST16));
  (void)hipFuncSetAttribute((const void*)crs_main, hipFuncAttributeMaxDynamicSharedMemorySize, LDS_TOTAL);
  hipLaunchKernelGGL(crs_main, dim3(NWG), dim3(TPB), LDS_TOTAL, stream,
                     x, st0, bfv, bcv, pg, pb, sg, sbv, y, ostate,
                     (const unsigned short*)(ws+WSO_WT), ws);
}